// Round 1
// baseline (149.647 us; speedup 1.0000x reference)
//
#include <hip/hip_runtime.h>
#include <math.h>

#define SLEN 53
#define NPIX (SLEN * SLEN)   // 2809
#define NPARAM 12            // 7 gal + b + cx + cy + e1 + e2

// One block per ptile (256 threads, ~11 pixels/thread).
// Unlensed image is an analytic Gaussian -> evaluate the 4 bilinear corner
// values directly (exact vs reference's materialize+gather), no LDS needed.
__global__ __launch_bounds__(256) void lgtd_kernel(
    const float* __restrict__ lens_params,
    const float* __restrict__ bools,
    float* __restrict__ out)
{
    const int tile = blockIdx.x;
    float* outp = out + (size_t)tile * NPIX;

    const float bl = bools[tile];
    if (bl == 0.0f) {
        // reference: out * bool == exactly 0; must still overwrite poison
        for (int idx = threadIdx.x; idx < NPIX; idx += blockDim.x)
            outp[idx] = 0.0f;
        return;
    }

    const float* p = lens_params + tile * NPARAM;   // uniform addr -> s_load
    // ---- per-tile galaxy params ----
    const float flux  = p[0] * 1000.0f + 100.0f;
    const float sigma = p[3] * 3.0f + 1.0f;
    const float s2    = sigma * sigma;
    const float A     = flux / (6.28318530717958647692f * s2); // flux/(2*pi*s2)
    const float nh    = -0.5f / s2;                            // exp coefficient
    // ---- per-tile lens params ----
    const float b  = p[7];
    const float cx = p[8], cy = p[9];
    const float e1 = p[10], e2 = p[11];
    const float ell    = sqrtf(e1 * e1 + e2 * e2);
    const float q      = (1.0f - ell) / (1.0f + ell);
    const float phirad = atanf(e2 / e1);
    const float cosp   = cosf(phirad);
    const float sinp   = sinf(phirad);
    const float qfact  = sqrtf(1.0f / q - q);
    const float eps    = 0.001f;
    const float safe   = fmaxf(qfact, eps);
    const float bos    = b / safe;
    const bool  main_branch = (qfact >= eps); // always true for this data, kept for fidelity

    for (int idx = threadIdx.x; idx < NPIX; idx += blockDim.x) {
        const int i = idx / SLEN;          // row    -> y
        const int j = idx - i * SLEN;      // column -> x
        // coords = (hi-lo)*arange/(nx-1) + lo = 53*k/52 - 27  (match ref op order)
        const float xc = 53.0f * (float)j / 52.0f - 27.0f;
        const float yc = 53.0f * (float)i / 52.0f - 27.0f;

        // ---- SIE deflection ----
        const float dx = xc - cx, dy = yc - cy;
        const float xsie = dx * cosp + dy * sinp;
        const float ysie = dy * cosp - dx * sinp;
        const float r_ell = sqrtf(q * xsie * xsie + ysie * ysie / q + 1e-12f);
        const float denom = r_ell;  // r_ell >= 1e-6 > 0, so (r_ell==0) term is 0
        float xtg, ytg;
        if (main_branch) {
            xtg = bos * atanf(safe * xsie / denom);
            ytg = bos * atanhf(safe * ysie / denom);
        } else {
            xtg = b * xsie / denom;
            ytg = b * ysie / denom;
        }
        const float xg = xtg * cosp - ytg * sinp;
        const float yg = ytg * cosp + xtg * sinp;

        // ---- bilinear sample coords ----
        const float xs = (xc - xg) + 26.0f;
        const float ys = (yc - yg) + 26.0f;
        const float fx = floorf(xs), fy = floorf(ys);
        const int x0i = (int)fx, y0i = (int)fy;
        const int x0 = min(max(x0i,     0), SLEN - 1);
        const int x1 = min(max(x0i + 1, 0), SLEN - 1);
        const int y0 = min(max(y0i,     0), SLEN - 1);
        const int y1 = min(max(y0i + 1, 0), SLEN - 1);
        const float x0f = (float)x0, x1f = (float)x1;
        const float y0f = (float)y0, y1f = (float)y1;
        const float wa = (x1f - xs) * (y1f - ys);
        const float wb = (x1f - xs) * (ys  - y0f);
        const float wc = (xs - x0f) * (y1f - ys);
        const float wd = (xs - x0f) * (ys  - y0f);

        // ---- analytic corner values of the unlensed Gaussian image ----
        const float cx0 = x0f - 26.0f, cx1 = x1f - 26.0f;
        const float cy0 = y0f - 26.0f, cy1 = y1f - 26.0f;
        const float sx0 = cx0 * cx0, sx1 = cx1 * cx1;
        const float sy0 = cy0 * cy0, sy1 = cy1 * cy1;
        const float g00 = A * expf(nh * (sx0 + sy0)); // g(y0,x0)
        const float g10 = A * expf(nh * (sx0 + sy1)); // g(y1,x0)
        const float g01 = A * expf(nh * (sx1 + sy0)); // g(y0,x1)
        const float g11 = A * expf(nh * (sx1 + sy1)); // g(y1,x1)

        const float val = g00 * wa + g10 * wb + g01 * wc + g11 * wd;
        outp[idx] = val * bl;
    }
}

extern "C" void kernel_launch(void* const* d_in, const int* in_sizes, int n_in,
                              void* d_out, int out_size, void* d_ws, size_t ws_size,
                              hipStream_t stream) {
    const float* lens  = (const float*)d_in[0];  // (N, 1, 12) fp32
    const float* bools = (const float*)d_in[1];  // (N, 1, 1)  fp32
    float* out = (float*)d_out;                  // (N, 1, 1, 53, 53) fp32
    const int n_tiles = in_sizes[1];             // = N_PTILES (one bool per tile)
    lgtd_kernel<<<n_tiles, 256, 0, stream>>>(lens, bools, out);
}

// Round 2
// 100.330 us; speedup vs baseline: 1.4915x; 1.4915x over previous
//
#include <hip/hip_runtime.h>
#include <math.h>

#define SLEN 53
#define NPIX (SLEN * SLEN)   // 2809
#define NPARAM 12            // 7 gal + b + cx + cy + e1 + e2

// Fast atan: 2-step Cephes range reduction + deg-4 poly in x^2.
// Max abs error ~2e-7 over full range (dominated by v_rcp ~1ulp).
__device__ __forceinline__ float fast_atan(float u) {
    float t = __builtin_fabsf(u);
    float rin = __builtin_amdgcn_rcpf(t);
    bool big = t > 1.0f;
    float w = big ? rin : t;                       // [0,1]
    bool mid = w > 0.4142135624f;                  // tan(pi/8)
    float w2 = (w - 1.0f) * __builtin_amdgcn_rcpf(w + 1.0f);
    float x = mid ? w2 : w;                        // [-0.4142, 0.4142]
    float z = x * x;
    float p = ((8.05374449538e-2f * z - 1.38776856032e-1f) * z
               + 1.99777106478e-1f) * z - 3.33329491539e-1f;
    float r = __builtin_fmaf(p * z, x, x);
    r = mid ? r + 0.78539816339744831f : r;
    r = big ? 1.57079632679489662f - r : r;
    return __builtin_copysignf(r, u);
}

// atanh(v) = 0.5*ln2*(log2(1+v) - log2(1-v)).  |v| <= sqrt(1-q^2) <= 0.995,
// so 1-v >= 0.005 and is computed exactly (Sterbenz) -> no cancellation.
__device__ __forceinline__ float fast_atanh(float v) {
    float a = __builtin_fabsf(v);
    float r = 0.34657359027997264f *
              (__builtin_amdgcn_logf(1.0f + a) - __builtin_amdgcn_logf(1.0f - a));
    return __builtin_copysignf(r, v);
}

// One block per ptile (256 threads, ~11 pixels/thread).
__global__ __launch_bounds__(256) void lgtd_kernel(
    const float* __restrict__ lens_params,
    const float* __restrict__ bools,
    float* __restrict__ out)
{
    const int tile = blockIdx.x;
    float* outp = out + (size_t)tile * NPIX;

    const float bl = bools[tile];
    if (bl == 0.0f) {
        for (int idx = threadIdx.x; idx < NPIX; idx += blockDim.x)
            outp[idx] = 0.0f;
        return;
    }

    const float* p = lens_params + tile * NPARAM;
    // ---- per-tile galaxy params (amortized over ~11 pixels/thread) ----
    const float flux  = p[0] * 1000.0f + 100.0f;
    const float sigma = p[3] * 3.0f + 1.0f;
    const float s2    = sigma * sigma;
    const float A     = bl * flux / (6.28318530717958647692f * s2);
    const float nh2   = -0.5f / s2 * 1.44269504088896340736f;  // exp2 coefficient
    // ---- per-tile lens params ----
    const float b  = p[7];
    const float cx = p[8], cy = p[9];
    const float e1 = p[10], e2 = p[11];
    const float ell    = sqrtf(e1 * e1 + e2 * e2);
    const float q      = (1.0f - ell) / (1.0f + ell);
    const float qinv   = 1.0f / q;
    const float phirad = atanf(e2 / e1);   // per-tile: libm is fine
    const float cosp   = cosf(phirad);
    const float sinp   = sinf(phirad);
    const float qfact  = sqrtf(qinv - q);
    const float eps    = 0.001f;
    const float safe   = fmaxf(qfact, eps);
    const float bos    = b / safe;
    const bool  main_branch = (qfact >= eps); // always true for this data

    for (int idx = threadIdx.x; idx < NPIX; idx += blockDim.x) {
        const int i = idx / SLEN;          // row    -> y
        const int j = idx - i * SLEN;      // column -> x
        const float xc = 53.0f * (float)j / 52.0f - 27.0f;
        const float yc = 53.0f * (float)i / 52.0f - 27.0f;

        // ---- SIE deflection ----
        const float dx = xc - cx, dy = yc - cy;
        const float xsie = dx * cosp + dy * sinp;
        const float ysie = dy * cosp - dx * sinp;
        const float arg = q * xsie * xsie + qinv * ysie * ysie + 1e-12f;
        const float rcp_r = __builtin_amdgcn_rsqf(arg);   // 1/r_ell, r_ell>=1e-6
        float xtg, ytg;
        if (main_branch) {
            xtg = bos * fast_atan(safe * xsie * rcp_r);
            ytg = bos * fast_atanh(safe * ysie * rcp_r);
        } else {
            xtg = b * xsie * rcp_r;
            ytg = b * ysie * rcp_r;
        }
        const float xg = xtg * cosp - ytg * sinp;
        const float yg = ytg * cosp + xtg * sinp;

        // ---- bilinear sample coords ----
        const float xs = (xc - xg) + 26.0f;
        const float ys = (yc - yg) + 26.0f;
        const float fx = floorf(xs), fy = floorf(ys);
        const int x0i = (int)fx, y0i = (int)fy;
        const int x0 = min(max(x0i,     0), SLEN - 1);
        const int x1 = min(max(x0i + 1, 0), SLEN - 1);
        const int y0 = min(max(y0i,     0), SLEN - 1);
        const int y1 = min(max(y0i + 1, 0), SLEN - 1);
        const float x0f = (float)x0, x1f = (float)x1;
        const float y0f = (float)y0, y1f = (float)y1;
        const float wa = (x1f - xs) * (y1f - ys);
        const float wb = (x1f - xs) * (ys  - y0f);
        const float wc = (xs - x0f) * (y1f - ys);
        const float wd = (xs - x0f) * (ys  - y0f);

        // ---- analytic corner values of the unlensed Gaussian (v_exp_f32) ----
        const float cx0 = x0f - 26.0f, cx1 = x1f - 26.0f;
        const float cy0 = y0f - 26.0f, cy1 = y1f - 26.0f;
        const float sx0 = cx0 * cx0, sx1 = cx1 * cx1;
        const float sy0 = cy0 * cy0, sy1 = cy1 * cy1;
        const float g00 = __builtin_amdgcn_exp2f(nh2 * (sx0 + sy0)); // g(y0,x0)
        const float g10 = __builtin_amdgcn_exp2f(nh2 * (sx0 + sy1)); // g(y1,x0)
        const float g01 = __builtin_amdgcn_exp2f(nh2 * (sx1 + sy0)); // g(y0,x1)
        const float g11 = __builtin_amdgcn_exp2f(nh2 * (sx1 + sy1)); // g(y1,x1)

        outp[idx] = A * (g00 * wa + g10 * wb + g01 * wc + g11 * wd);
    }
}

extern "C" void kernel_launch(void* const* d_in, const int* in_sizes, int n_in,
                              void* d_out, int out_size, void* d_ws, size_t ws_size,
                              hipStream_t stream) {
    const float* lens  = (const float*)d_in[0];  // (N, 1, 12) fp32
    const float* bools = (const float*)d_in[1];  // (N, 1, 1)  fp32
    float* out = (float*)d_out;                  // (N, 1, 1, 53, 53) fp32
    const int n_tiles = in_sizes[1];
    lgtd_kernel<<<n_tiles, 256, 0, stream>>>(lens, bools, out);
}

// Round 3
// 88.073 us; speedup vs baseline: 1.6991x; 1.1392x over previous
//
#include <hip/hip_runtime.h>
#include <math.h>

#define SLEN 53
#define NPIX (SLEN * SLEN)   // 2809
#define NPARAM 12            // 7 gal + b + cx + cy + e1 + e2
#define BLK 256
#define NITER ((NPIX + BLK - 1) / BLK)   // 11

// Fast atan: 2-step Cephes range reduction + deg-4 poly in x^2.
// Max abs error ~2e-7 over full range (dominated by v_rcp ~1ulp).
__device__ __forceinline__ float fast_atan(float u) {
    float t = __builtin_fabsf(u);
    float rin = __builtin_amdgcn_rcpf(t);
    bool big = t > 1.0f;
    float w = big ? rin : t;                       // [0,1]
    bool mid = w > 0.4142135624f;                  // tan(pi/8)
    float w2 = (w - 1.0f) * __builtin_amdgcn_rcpf(w + 1.0f);
    float x = mid ? w2 : w;                        // [-0.4142, 0.4142]
    float z = x * x;
    float p = ((8.05374449538e-2f * z - 1.38776856032e-1f) * z
               + 1.99777106478e-1f) * z - 3.33329491539e-1f;
    float r = __builtin_fmaf(p * z, x, x);
    r = mid ? r + 0.78539816339744831f : r;
    r = big ? 1.57079632679489662f - r : r;
    return __builtin_copysignf(r, u);
}

// atanh(v) = 0.5*ln2*(log2(1+v) - log2(1-v)).  |v| <= sqrt(1-q^2) <= 0.995,
// so 1-v >= 0.005 and exact (Sterbenz) -> no cancellation.
__device__ __forceinline__ float fast_atanh(float v) {
    float a = __builtin_fabsf(v);
    float r = 0.34657359027997264f *
              (__builtin_amdgcn_logf(1.0f + a) - __builtin_amdgcn_logf(1.0f - a));
    return __builtin_copysignf(r, v);
}

// One block per ptile. Separable Gaussian: bilinear(im, xs, ys) =
// A * [(x1-xs)E[x0]+(xs-x0)E[x1]] * [(y1-ys)E[y0]+(ys-y0)E[y1]],
// E[k]=exp2(nh2*(k-26)^2) staged in LDS (53 exps/tile, not 4/pixel).
__global__ __launch_bounds__(BLK) void lgtd_kernel(
    const float* __restrict__ lens_params,
    const float* __restrict__ bools,
    float* __restrict__ out)
{
    const int tile = blockIdx.x;
    float* outp = out + (size_t)tile * NPIX;
    const int tid = threadIdx.x;

    const float bl = bools[tile];
    if (bl == 0.0f) {
        int idx = tid;
        #pragma unroll
        for (int it = 0; it < NITER; ++it, idx += BLK)
            if (it < NITER - 1 || idx < NPIX) outp[idx] = 0.0f;
        return;
    }

    const float* p = lens_params + tile * NPARAM;   // uniform -> s_load
    // ---- per-tile galaxy params ----
    const float flux  = p[0] * 1000.0f + 100.0f;
    const float sigma = p[3] * 3.0f + 1.0f;
    const float s2    = sigma * sigma;
    const float A     = bl * flux / (6.28318530717958647692f * s2);
    const float nh2   = -0.5f / s2 * 1.44269504088896340736f;  // exp2 coeff
    // ---- per-tile lens params ----
    const float b  = p[7];
    const float cx = p[8], cy = p[9];
    const float e1 = p[10], e2 = p[11];
    const float ell    = sqrtf(e1 * e1 + e2 * e2);
    const float q      = (1.0f - ell) / (1.0f + ell);
    const float qinv   = 1.0f / q;
    const float phirad = atanf(e2 / e1);   // once per tile: libm ok
    const float cosp   = cosf(phirad);
    const float sinp   = sinf(phirad);
    const float qfact  = sqrtf(qinv - q);
    const float eps    = 0.001f;
    const float safe   = fmaxf(qfact, eps);
    const float bos    = b / safe;
    const bool  main_branch = (qfact >= eps); // always true for this data

    // ---- per-tile LDS tables: exact ref coords + Gaussian 1D profile ----
    __shared__ float Ctab[SLEN];   // 53*k/52 - 27  (exact ref op order)
    __shared__ float Etab[SLEN];   // exp2(nh2*(k-26)^2)
    if (tid < SLEN) {
        const float kf = (float)tid;
        Ctab[tid] = 53.0f * kf / 52.0f - 27.0f;
        const float d = kf - 26.0f;
        Etab[tid] = __builtin_amdgcn_exp2f(nh2 * (d * d));
    }
    __syncthreads();

    int idx = tid;
    #pragma unroll
    for (int it = 0; it < NITER; ++it, idx += BLK) {
        if (it == NITER - 1 && idx >= NPIX) break;
        const int i = idx / SLEN;          // row    -> y
        const int j = idx - i * SLEN;      // column -> x
        const float xc = Ctab[j];
        const float yc = Ctab[i];

        // ---- SIE deflection ----
        const float dx = xc - cx, dy = yc - cy;
        const float xsie = dx * cosp + dy * sinp;
        const float ysie = dy * cosp - dx * sinp;
        const float arg = q * xsie * xsie + qinv * ysie * ysie + 1e-12f;
        const float rcp_r = __builtin_amdgcn_rsqf(arg);   // 1/r_ell
        float xtg, ytg;
        if (main_branch) {
            xtg = bos * fast_atan(safe * xsie * rcp_r);
            ytg = bos * fast_atanh(safe * ysie * rcp_r);
        } else {
            xtg = b * xsie * rcp_r;
            ytg = b * ysie * rcp_r;
        }
        const float xg = xtg * cosp - ytg * sinp;
        const float yg = ytg * cosp + xtg * sinp;

        // ---- bilinear sample coords ----
        const float xs = (xc - xg) + 26.0f;
        const float ys = (yc - yg) + 26.0f;
        const int x0i = (int)floorf(xs), y0i = (int)floorf(ys);
        const int x0 = min(max(x0i,     0), SLEN - 1);
        const int x1 = min(max(x0i + 1, 0), SLEN - 1);
        const int y0 = min(max(y0i,     0), SLEN - 1);
        const int y1 = min(max(y0i + 1, 0), SLEN - 1);
        const float x0f = (float)x0, x1f = (float)x1;
        const float y0f = (float)y0, y1f = (float)y1;

        // ---- separable bilinear of the Gaussian ----
        const float Fx = (x1f - xs) * Etab[x0] + (xs - x0f) * Etab[x1];
        const float Fy = (y1f - ys) * Etab[y0] + (ys - y0f) * Etab[y1];
        outp[idx] = A * Fx * Fy;
    }
}

extern "C" void kernel_launch(void* const* d_in, const int* in_sizes, int n_in,
                              void* d_out, int out_size, void* d_ws, size_t ws_size,
                              hipStream_t stream) {
    const float* lens  = (const float*)d_in[0];  // (N, 1, 12) fp32
    const float* bools = (const float*)d_in[1];  // (N, 1, 1)  fp32
    float* out = (float*)d_out;                  // (N, 1, 1, 53, 53) fp32
    const int n_tiles = in_sizes[1];
    lgtd_kernel<<<n_tiles, BLK, 0, stream>>>(lens, bools, out);
}